// Round 5
// baseline (169.297 us; speedup 1.0000x reference)
//
#include <hip/hip_runtime.h>
#include <math.h>

#define BB 2
#define LSEQ 2048
#define H 32
#define PDIM 64
#define NDIM 128
#define CS 256
#define NC 8

typedef _Float16 half8 __attribute__((ext_vector_type(8)));
typedef _Float16 half4 __attribute__((ext_vector_type(4)));
typedef float floatx4 __attribute__((ext_vector_type(4)));

// ---------------- ws layout (bytes) ----------------
// cum      : f32 [bz=16][H][CS]               @ 0          (512 KB)
// cdecay   : f32 [bz][H]                      @ 524288     (2 KB)
// CBt      : f32 [bz][l16=16][s8=32][16][8]   @ 526336     (4 MB)   MFMA-tiled
// states   : f32 [bzh=512][PDIM][NDIM]        @ 4720640    (16 MB)
// xTdtT    : f16 [bzh][p16=4][s8=32][16][8]   @ 21497856   (16 MB)  x*dtf*xs, tiled
// statesHT : f16 [bzh][p16=4][n8=16][16][8]   @ 38275072   (8 MB)   prev-state/16
// Bt16T    : f16 [bz][n16=8][s8=32][16][8]    @ 46663680   (1 MB)
// C16T     : f16 [bz][l16=16][n8=16][16][8]   @ 47712256   (1 MB)
// x8       : i8  [b][l][h][p]                 @ 48760832   (8 MB)

__device__ __forceinline__ int dot4i8(int a, int b, int c) {
#if __has_builtin(__builtin_amdgcn_sdot4)
    return __builtin_amdgcn_sdot4(a, b, c, false);
#else
    c += ((a << 24) >> 24) * ((b << 24) >> 24);
    c += ((a << 16) >> 24) * ((b << 16) >> 24);
    c += ((a << 8) >> 24) * ((b << 8) >> 24);
    c += (a >> 24) * (b >> 24);
    return c;
#endif
}

// kA: merged CBt Gram (causal tiles) + Bt16T/C16T prep
__global__ __launch_bounds__(256) void kA(
    const int* __restrict__ Bm, const int* __restrict__ Cm,
    const float* __restrict__ Bs_p, const float* __restrict__ Cs_p,
    float* __restrict__ CBt, _Float16* __restrict__ Bt16T, _Float16* __restrict__ C16T)
{
    __shared__ int Bi[64][33];
    __shared__ int Ci[64][33];
    int t = threadIdx.x;
    int r = blockIdx.x % 26;
    int zz = blockIdx.x / 26;
    int z = zz & 7, b = zz >> 3;
    int bz = b * NC + z;
    if (r < 10) {
        const int LT[10] = {0,1,1,2,2,2,3,3,3,3};
        const int ST[10] = {0,0,1,0,1,2,0,1,2,3};
        int l0 = LT[r] * 64, s0 = ST[r] * 64;
        const int* Bp = Bm + (size_t)(b * LSEQ + z * CS + s0) * NDIM;
        const int* Cp = Cm + (size_t)(b * LSEQ + z * CS + l0) * NDIM;
        for (int i = t; i < 64 * 32; i += 256) {
            int rr = i >> 5, k = i & 31;
            const int* sb = Bp + rr * NDIM + k * 4;
            const int* sc = Cp + rr * NDIM + k * 4;
            Bi[rr][k] = (sb[0] & 255) | ((sb[1] & 255) << 8) | ((sb[2] & 255) << 16) | ((sb[3] & 255) << 24);
            Ci[rr][k] = (sc[0] & 255) | ((sc[1] & 255) << 8) | ((sc[2] & 255) << 16) | ((sc[3] & 255) << 24);
        }
        __syncthreads();
        float cbscale = (*Bs_p) * (*Cs_p);
        int ll = t & 63, lg = t >> 6;
        int acc[16];
#pragma unroll
        for (int i = 0; i < 16; ++i) acc[i] = 0;
        for (int k = 0; k < 32; ++k) {
            int cw = Ci[ll][k];
#pragma unroll
            for (int si = 0; si < 16; ++si)
                acc[si] = dot4i8(cw, Bi[lg * 16 + si][k], acc[si]);
        }
        int l = l0 + ll;
        int l16 = l >> 4, lm = l & 15;
        int sb8 = (s0 + lg * 16) >> 3;
        float* bp = CBt + ((size_t)(bz * 16 + l16) * 32 + sb8) * 128 + lm * 8;
#pragma unroll
        for (int g = 0; g < 2; ++g) {
            floatx4 v0, v1;
#pragma unroll
            for (int i = 0; i < 4; ++i) {
                v0[i] = (float)acc[g * 8 + i] * cbscale;
                v1[i] = (float)acc[g * 8 + 4 + i] * cbscale;
            }
            *(floatx4*)(bp + g * 128) = v0;
            *(floatx4*)(bp + g * 128 + 4) = v1;
        }
    } else {
        int slice = r - 10;   // 0..15
        {   // C16T: l16 = slice
            int lm = t >> 4, n8 = t & 15;
            const int* cp = Cm + (size_t)(b * LSEQ + z * CS + slice * 16 + lm) * NDIM + n8 * 8;
            int4 c0 = *(const int4*)cp;
            int4 c1 = *(const int4*)(cp + 4);
            half8 v;
            v[0] = (_Float16)(float)c0.x; v[1] = (_Float16)(float)c0.y;
            v[2] = (_Float16)(float)c0.z; v[3] = (_Float16)(float)c0.w;
            v[4] = (_Float16)(float)c1.x; v[5] = (_Float16)(float)c1.y;
            v[6] = (_Float16)(float)c1.z; v[7] = (_Float16)(float)c1.w;
            *(half8*)(C16T + ((size_t)(bz * 16 + slice) * 16 + n8) * 128 + lm * 8) = v;
        }
        {   // Bt16T transpose: n16 = slice&7, s-half = slice>>3
            int nm = t & 15, s8l = t >> 4;
            int n16 = slice & 7, s8 = (slice >> 3) * 16 + s8l;
            const int* bp = Bm + (size_t)(b * LSEQ + z * CS + s8 * 8) * NDIM + n16 * 16 + nm;
            half8 v;
#pragma unroll
            for (int j = 0; j < 8; ++j) v[j] = (_Float16)(float)bp[(size_t)j * NDIM];
            *(half8*)(Bt16T + ((size_t)(bz * 8 + n16) * 32 + s8) * 128 + nm * 8) = v;
        }
    }
}

// k013: fused softplus/cumsum + x transpose + states MFMA.
// grid 1024: one block per (b,z,h,p-half) -> 4 blocks/CU occupancy.
#define XC_PITCH 132    // 128 + 4 halfs pad -> free 2-way LDS bank aliasing
__global__ __launch_bounds__(256) void k013(
    const int* __restrict__ dt, const int* __restrict__ qA, const float* __restrict__ dt_bias,
    const float* __restrict__ A_scale_p, const float* __restrict__ dt_scale_p,
    const int* __restrict__ xq, const float* __restrict__ xs_p, const float* __restrict__ Bs_p,
    const _Float16* __restrict__ Bt16T,
    float* __restrict__ cum, float* __restrict__ cdecay,
    _Float16* __restrict__ xTdtT, signed char* __restrict__ x8,
    float* __restrict__ states)
{
    __shared__ float cumS[CS];
    __shared__ float cA[CS], cB[CS];
    __shared__ float wsum[4];
    __shared__ _Float16 xcS[2 * 32 * XC_PITCH];
    int t = threadIdx.x;
    int half = blockIdx.x & 1;
    int h = (blockIdx.x >> 1) & 31, z = (blockIdx.x >> 6) & 7, b = blockIdx.x >> 9;
    int bz = b * NC + z, bzh = bz * H + h;
    int lane6 = t & 63, w = t >> 6;

    // --- softplus + wave-shuffle inclusive scan (redone per half; cheap) ---
    float A = -__expf((float)qA[h] * (*A_scale_p));
    float raw = (float)dt[(size_t)(b * LSEQ + z * CS + t) * H + h];
    float xin = raw * (*dt_scale_p) + dt_bias[h];
    float sp = (xin > 20.f) ? xin : log1pf(__expf(xin));
    float v = sp * A;
#pragma unroll
    for (int off = 1; off < 64; off <<= 1) {
        float u = __shfl_up(v, off, 64);
        if (lane6 >= off) v += u;
    }
    if (lane6 == 63) wsum[w] = v;
    __syncthreads();
    float add = 0.f;
    for (int wv = 0; wv < w; ++wv) add += wsum[wv];
    float cumv = v + add;
    float cl = wsum[0] + wsum[1] + wsum[2] + wsum[3];
    float xs = *xs_p;
    if (half == 0) {
        cum[bzh * CS + t] = cumv;
        if (t == 0) cdecay[bzh] = __expf(cl);
    }
    cumS[t] = cumv;
    cA[t] = sp * xs;
    cB[t] = sp * __expf(cl - cumv) * xs * (*Bs_p);
    __syncthreads();

    // --- x load/transpose (32 of 64 p): xTdt->global, xc->LDS, x8->global ---
    int s8 = t & 31, pq = t >> 5;            // pq 0..7: p = half*32 + pq*4 .. +4
    const int* xb = xq + ((size_t)(b * LSEQ + z * CS) * H + h) * PDIM + half * 32 + pq * 4;
    signed char* x8b = x8 + ((size_t)(b * LSEQ + z * CS) * H + h) * PDIM + half * 32 + pq * 4;
    {
        half8 va[4], vc[4];
#pragma unroll
        for (int j = 0; j < 8; ++j) {
            int s = s8 * 8 + j;
            int4 w4 = *(const int4*)(xb + (size_t)s * (H * PDIM));
            float a = cA[s], c = cB[s];
            signed char pk[4];
#define CVT(PL, V) { float xv = (float)(V); va[PL][j] = (_Float16)(xv * a); vc[PL][j] = (_Float16)(xv * c); pk[PL] = (signed char)(V); }
            CVT(0, w4.x) CVT(1, w4.y) CVT(2, w4.z) CVT(3, w4.w)
#undef CVT
            *(int*)pk;   // keep
            *(int*)(x8b + (size_t)s * (H * PDIM)) = *(int*)pk;
        }
#pragma unroll
        for (int pl = 0; pl < 4; ++pl) {
            int ploc = pq * 4 + pl;           // 0..31 within half
            int p16l = ploc >> 4, pm = ploc & 15;
            *(half8*)(xTdtT + ((size_t)(bzh * 4 + half * 2 + p16l) * 32 + s8) * 128 + pm * 8) = va[pl];
            *(half8*)(xcS + (p16l * 32 + s8) * XC_PITCH + pm * 8) = vc[pl];
        }
    }
    __syncthreads();

    // --- states MFMA: wave w -> p16l = w&1, nt-half = w>>1 ---
    int m = lane6 & 15, q = lane6 >> 4;
    int p16l = w & 1, ntb = (w >> 1) * 4;
    const _Float16* abase = xcS + (p16l * 32) * XC_PITCH + m * 8;
    const _Float16* bbase = Bt16T + ((size_t)(bz * 8 + ntb) * 32) * 128 + m * 8;
    floatx4 acc[4] = {};
    for (int kk = 0; kk < 8; ++kk) {
        if (cl - cumS[kk * 32 + 31] < -30.f) continue;   // fp16-exact-0 chunk skip
        int s8k = kk * 4 + q;
        half8 a = *(const half8*)(abase + s8k * XC_PITCH);
#pragma unroll
        for (int i = 0; i < 4; ++i) {
            half8 bf = *(const half8*)(bbase + ((size_t)i * 32 + s8k) * 128);
            acc[i] = __builtin_amdgcn_mfma_f32_16x16x32_f16(a, bf, acc[i], 0, 0, 0);
        }
    }
    int p16 = half * 2 + p16l;
    float* sb = states + (size_t)bzh * (PDIM * NDIM);
#pragma unroll
    for (int i = 0; i < 4; ++i)
#pragma unroll
        for (int rr = 0; rr < 4; ++rr)
            sb[(size_t)(p16 * 16 + q * 4 + rr) * NDIM + (ntb + i) * 16 + m] = acc[i][rr];
}

// k4: sequential inter-chunk scan (float4), emits fp16 tiled statesHT (prev/16)
__global__ __launch_bounds__(256) void k4_scan(
    const float* __restrict__ cdecay, const float* __restrict__ states,
    _Float16* __restrict__ statesHT)
{
    int idx = blockIdx.x * 256 + threadIdx.x;
    int n4 = (idx & 31) * 4, p = (idx >> 5) & 63, h = (idx >> 11) & 31, b = idx >> 16;
    int soff = p * 128 + n4;
    int toff = ((p >> 4) * 16 + (n4 >> 3)) * 128 + (p & 15) * 8 + (n4 & 7);
    floatx4 carry = {};
    for (int z = 0; z < NC; ++z) {
        int bzh = (b * NC + z) * H + h;
        floatx4 v = *(const floatx4*)(states + (size_t)bzh * 8192 + soff);
        float d = cdecay[bzh];
        half4 o;
#pragma unroll
        for (int i = 0; i < 4; ++i) o[i] = (_Float16)(carry[i] * 0.0625f);
        *(half4*)(statesHT + (size_t)bzh * 8192 + toff) = o;
#pragma unroll
        for (int i = 0; i < 4; ++i) carry[i] = d * carry[i] + v[i];
    }
}

// k56: fused inter+intra+D. grid 1024: (b,z,h) x l16-parity.
// wave w owns parity tiles {w, 7-w} -> 9 causal k-steps each (balanced).
__global__ __launch_bounds__(256) void k56(
    const signed char* __restrict__ x8, const int* __restrict__ qD,
    const float* __restrict__ cum, const float* __restrict__ CBt,
    const _Float16* __restrict__ xTdtT, const _Float16* __restrict__ C16T,
    const _Float16* __restrict__ statesHT,
    const float* __restrict__ Cs_p, const float* __restrict__ xs_p, const float* __restrict__ Ds_p,
    float* __restrict__ out)
{
    __shared__ float cumL[CS];
    __shared__ float ep[128][65];
    int t = threadIdx.x;
    int parity = blockIdx.x & 1;
    int h = (blockIdx.x >> 1) & 31, z = (blockIdx.x >> 6) & 7, b = blockIdx.x >> 9;
    int bz = b * NC + z, bzh = bz * H + h;
    cumL[t] = cum[bzh * CS + t];
    __syncthreads();
    int w = t >> 6, lane = t & 63, m = lane & 15, q = lane >> 4;
    int l16a[2] = {parity + 2 * w, parity + 2 * (7 - w)};
    floatx4 acc[2][4] = {};   // [j][pt]

    // ---- inter phase: acc = C_raw @ (prev/16) ----
    const _Float16* shb = statesHT + (size_t)bzh * 8192 + m * 8;
    const _Float16* cbase = C16T + (size_t)bz * 16 * 16 * 128 + m * 8;
    bool interact[2];
#pragma unroll
    for (int j = 0; j < 2; ++j) interact[j] = (cumL[l16a[j] * 16] > -80.f);
    for (int kk = 0; kk < 4; ++kk) {
        int n8 = kk * 4 + q;
        half8 bf[4];
#pragma unroll
        for (int pt = 0; pt < 4; ++pt)
            bf[pt] = *(const half8*)(shb + (pt * 16 + n8) * 128);
#pragma unroll
        for (int j = 0; j < 2; ++j) {
            if (!interact[j]) continue;
            half8 ha = *(const half8*)(cbase + ((size_t)l16a[j] * 16 + n8) * 128);
#pragma unroll
            for (int pt = 0; pt < 4; ++pt)
                acc[j][pt] = __builtin_amdgcn_mfma_f32_16x16x32_f16(ha, bf[pt], acc[j][pt], 0, 0, 0);
        }
    }
    float Cs16 = (*Cs_p) * 16.0f;
#pragma unroll
    for (int j = 0; j < 2; ++j)
#pragma unroll
        for (int r = 0; r < 4; ++r) {
            float e = __expf(cumL[l16a[j] * 16 + q * 4 + r]) * Cs16;
#pragma unroll
            for (int pt = 0; pt < 4; ++pt) acc[j][pt][r] *= e;
        }

    // ---- intra phase ----
    const float* cbtb = CBt + (size_t)bz * 16 * 32 * 128 + m * 8;
    const _Float16* xb = xTdtT + (size_t)bzh * 4 * 32 * 128 + m * 8;
    for (int kk = 0; kk < 8; ++kk) {
        bool ex[2];
#pragma unroll
        for (int j = 0; j < 2; ++j)
            ex[j] = (2 * kk <= l16a[j]) && (cumL[l16a[j] * 16] - cumL[kk * 32 + 31] >= -30.f);
        if (!ex[0] && !ex[1]) continue;
        int s8 = kk * 4 + q;
        half8 bf[4];
#pragma unroll
        for (int pt = 0; pt < 4; ++pt)
            bf[pt] = *(const half8*)(xb + ((size_t)pt * 32 + s8) * 128);
#pragma unroll
        for (int j = 0; j < 2; ++j) {
            if (!ex[j]) continue;
            int l16 = l16a[j];
            int lA = l16 * 16 + m;
            float cum_l = cumL[lA];
            const float* cp = cbtb + ((size_t)l16 * 32 + s8) * 128;
            floatx4 c0 = *(const floatx4*)cp;
            floatx4 c1 = *(const floatx4*)(cp + 4);
            half8 a;
#pragma unroll
            for (int jj = 0; jj < 8; ++jj) {
                int s = kk * 32 + q * 8 + jj;
                float cb = (jj < 4) ? c0[jj] : c1[jj - 4];
                float wv = cb * __expf(cum_l - cumL[s]);
                a[jj] = (_Float16)((s <= lA) ? wv : 0.f);
            }
#pragma unroll
            for (int pt = 0; pt < 4; ++pt)
                acc[j][pt] = __builtin_amdgcn_mfma_f32_16x16x32_f16(a, bf[pt], acc[j][pt], 0, 0, 0);
        }
    }

    // ---- epilogue: LDS transpose -> coalesced float4 out, + D*x ----
    float xsDf = (*xs_p) * ((float)qD[h] * (*Ds_p));
    __syncthreads();
#pragma unroll
    for (int j = 0; j < 2; ++j) {
        int kidx = (j == 0) ? w : 7 - w;
        int lbase = kidx * 16 + q * 4;
#pragma unroll
        for (int r = 0; r < 4; ++r)
#pragma unroll
            for (int pt = 0; pt < 4; ++pt)
                ep[lbase + r][pt * 16 + m] = acc[j][pt][r];
    }
    __syncthreads();
    int lloc = t >> 1;                      // 0..127
    int kidx = lloc >> 4, row = lloc & 15;
    int l = (parity + 2 * kidx) * 16 + row;
    size_t go = ((size_t)(b * LSEQ + z * CS + l) * H + h) * PDIM + (t & 1) * 32;
    const float* er = &ep[lloc][(t & 1) * 32];
    const signed char* xp8 = x8 + go;
#pragma unroll
    for (int it = 0; it < 8; ++it) {
        int xw = *(const int*)(xp8 + it * 4);
        floatx4 vv;
        vv[0] = er[it * 4 + 0] + (float)((xw << 24) >> 24) * xsDf;
        vv[1] = er[it * 4 + 1] + (float)((xw << 16) >> 24) * xsDf;
        vv[2] = er[it * 4 + 2] + (float)((xw << 8) >> 24) * xsDf;
        vv[3] = er[it * 4 + 3] + (float)(xw >> 24) * xsDf;
        *(floatx4*)(out + go + it * 4) = vv;
    }
}

extern "C" void kernel_launch(void* const* d_in, const int* in_sizes, int n_in,
                              void* d_out, int out_size, void* d_ws, size_t ws_size,
                              hipStream_t stream)
{
    const int* xq = (const int*)d_in[0];
    const int* dt = (const int*)d_in[1];
    const int* Bm = (const int*)d_in[2];
    const int* Cm = (const int*)d_in[3];
    const int* qA = (const int*)d_in[4];
    const int* qD = (const int*)d_in[5];
    const float* dt_bias = (const float*)d_in[6];
    const float* A_scale = (const float*)d_in[7];
    const float* D_scale = (const float*)d_in[8];
    const float* dt_scale = (const float*)d_in[9];
    const float* x_scale = (const float*)d_in[10];
    const float* B_scale = (const float*)d_in[11];
    const float* C_scale = (const float*)d_in[12];
    float* out = (float*)d_out;

    char* ws = (char*)d_ws;
    float* cum          = (float*)(ws);
    float* cdecay       = (float*)(ws + 524288);
    float* CBt          = (float*)(ws + 526336);
    float* states       = (float*)(ws + 4720640);
    _Float16* xTdtT     = (_Float16*)(ws + 21497856);
    _Float16* statesHT  = (_Float16*)(ws + 38275072);
    _Float16* Bt16T     = (_Float16*)(ws + 46663680);
    _Float16* C16T      = (_Float16*)(ws + 47712256);
    signed char* x8     = (signed char*)(ws + 48760832);

    kA<<<dim3(416), dim3(256), 0, stream>>>(Bm, Cm, B_scale, C_scale, CBt, Bt16T, C16T);
    k013<<<dim3(1024), dim3(256), 0, stream>>>(dt, qA, dt_bias, A_scale, dt_scale,
                                               xq, x_scale, B_scale, Bt16T,
                                               cum, cdecay, xTdtT, x8, states);
    k4_scan<<<dim3(512), dim3(256), 0, stream>>>(cdecay, states, statesHT);
    k56<<<dim3(1024), dim3(256), 0, stream>>>(x8, qD, cum, CBt, xTdtT, C16T, statesHT,
                                              C_scale, x_scale, D_scale, out);
}